// Round 12
// baseline (79.533 us; speedup 1.0000x reference)
//
#include <hip/hip_runtime.h>
#include <stdint.h>

#define VSZ   192   // floats of per-view data (186 used, padded)
#define NTHR  256
#define WRECS 16           // records per wave
#define WIN_F (WRECS * 82) // 1312 floats staged per wave
#define WV_F  1520         // per-wave union region (output layout size)
// per-wave output section offsets (floats):
#define WM  0     // means  48
#define WS  48    // scales 48
#define WC  96    // cov    144
#define WQ  240   // quats  64
#define WO  304   // op     16
#define WSH 320   // sh     1200

typedef float vf4 __attribute__((ext_vector_type(4)));   // legal nt-store operand
typedef const __attribute__((address_space(1))) uint32_t* gas_ptr;
typedef __attribute__((address_space(3))) uint32_t* las_ptr;
__device__ __forceinline__ void g2lds16(const float4* g, float4* l) {
    __builtin_amdgcn_global_load_lds((gas_ptr)(const void*)g, (las_ptr)(void*)l, 16, 0, 0);
}

// ---------------- SH basis (degree 4, 25 components), float ----------------
__device__ __forceinline__ void sh_basis25(float x, float y, float z, float* Y) {
    float x2 = x * x, y2 = y * y, z2 = z * z;
    Y[0]  = 0.2820947918f;
    Y[1]  = 0.4886025119f * y;
    Y[2]  = 0.4886025119f * z;
    Y[3]  = 0.4886025119f * x;
    Y[4]  = 1.0925484306f * x * y;
    Y[5]  = 1.0925484306f * y * z;
    Y[6]  = 0.3153915653f * (3.0f * z2 - 1.0f);
    Y[7]  = 1.0925484306f * x * z;
    Y[8]  = 0.5462742153f * (x2 - y2);
    Y[9]  = 0.5900435899f * y * (3.0f * x2 - y2);
    Y[10] = 2.8906114426f * x * y * z;
    Y[11] = 0.4570457995f * y * (5.0f * z2 - 1.0f);
    Y[12] = 0.3731763326f * z * (5.0f * z2 - 3.0f);
    Y[13] = 0.4570457995f * x * (5.0f * z2 - 1.0f);
    Y[14] = 1.4453057213f * z * (x2 - y2);
    Y[15] = 0.5900435899f * x * (x2 - 3.0f * y2);
    Y[16] = 2.5033429418f * x * y * (x2 - y2);
    Y[17] = 1.7701307698f * y * z * (3.0f * x2 - y2);
    Y[18] = 0.9461746958f * x * y * (7.0f * z2 - 1.0f);
    Y[19] = 0.6690465436f * y * z * (7.0f * z2 - 3.0f);
    Y[20] = 0.1057855469f * (35.0f * z2 * z2 - 30.0f * z2 + 3.0f);
    Y[21] = 0.6690465436f * x * z * (7.0f * z2 - 3.0f);
    Y[22] = 0.4730873479f * (x2 - y2) * (7.0f * z2 - 1.0f);
    Y[23] = 1.7701307698f * x * z * (x2 - 3.0f * y2);
    Y[24] = 0.6258357354f * (x2 * x2 - 6.0f * x2 * y2 + y2 * y2);
}

// Per-view data layout (floats):
// [0:9) R_c2w  [9:12) cam_o  [12:21) Kinv  [21] scale_adj
// [22:31) D1   [31:56) D2    [56:105) D3   [105:186) D4
__global__ __launch_bounds__(64) void setup_kernel(
        const float* __restrict__ ext,
        const float* __restrict__ intr,
        const int* __restrict__ ph,
        const int* __restrict__ pw,
        float* __restrict__ vdg) {
    __shared__ float Bs[24][9];
    __shared__ float Yrs[24][9];
    __shared__ float normInv[24];

    int bv = blockIdx.x;
    int tid = threadIdx.x;
    const float* E = ext + bv * 16;
    const float* K = intr + bv * 9;
    float* o = vdg + bv * VSZ;

    const float z0 = 0.5f, r0 = 0.8660254037844386f;  // sqrt(3)/2
    const float TWO_PI = 6.283185307179586f;

    if (tid < 24) {
        int l, base;
        if      (tid < 3)  { l = 1; base = 0;  }
        else if (tid < 8)  { l = 2; base = 3;  }
        else if (tid < 15) { l = 3; base = 8;  }
        else               { l = 4; base = 15; }
        int n  = 2 * l + 1;
        int si = tid - base;
        int lo = l * l;
        float phs = 0.4f + TWO_PI * (float)si / (float)n;
        float sx = r0 * cosf(phs), sy = r0 * sinf(phs), sz = z0;
        float Y[25];
        sh_basis25(sx, sy, sz, Y);
        for (int k = 0; k < n; k++) Bs[tid][k] = Y[lo + k];
        float dx = E[0] * sx + E[1] * sy + E[2]  * sz;
        float dy = E[4] * sx + E[5] * sy + E[6]  * sz;
        float dz = E[8] * sx + E[9] * sy + E[10] * sz;
        sh_basis25(dx, dy, dz, Y);
        for (int k = 0; k < n; k++) Yrs[tid][k] = Y[lo + k];
    }
    __syncthreads();

    if (tid < 24) {
        int l, base;
        if      (tid < 3)  { l = 1; base = 0;  }
        else if (tid < 8)  { l = 2; base = 3;  }
        else if (tid < 15) { l = 3; base = 8;  }
        else               { l = 4; base = 15; }
        int n = 2 * l + 1;
        int m = tid - base;
        float acc = 0.f;
        for (int s = 0; s < n; s++) { float v = Bs[base + s][m]; acc += v * v; }
        normInv[tid] = 1.0f / acc;
    }
    __syncthreads();

    const int dofs[5] = {0, 22, 31, 56, 105};
    for (int e = tid; e < 164; e += 64) {
        int l, ebase, sbase;
        if      (e < 9)  { l = 1; ebase = 0;  sbase = 0;  }
        else if (e < 34) { l = 2; ebase = 9;  sbase = 3;  }
        else if (e < 83) { l = 3; ebase = 34; sbase = 8;  }
        else             { l = 4; ebase = 83; sbase = 15; }
        int n = 2 * l + 1;
        int el = e - ebase;
        int m = el / n, k = el % n;
        float acc = 0.f;
        for (int s = 0; s < n; s++) acc += Yrs[sbase + s][k] * Bs[sbase + s][m];
        o[dofs[l] + m * n + k] = acc * normInv[sbase + m];
    }

    if (tid == 0) {
        float Rw2c[3][3], Rc2w[3][3], t[3];
        for (int i = 0; i < 3; i++) {
            for (int j = 0; j < 3; j++) Rw2c[i][j] = E[i * 4 + j];
            t[i] = E[i * 4 + 3];
        }
        for (int i = 0; i < 3; i++)
            for (int j = 0; j < 3; j++) Rc2w[i][j] = Rw2c[j][i];
        for (int i = 0; i < 3; i++)
            for (int j = 0; j < 3; j++) o[i * 3 + j] = Rc2w[i][j];
        for (int i = 0; i < 3; i++) {
            float s = 0.f;
            for (int j = 0; j < 3; j++) s += Rc2w[i][j] * t[j];
            o[9 + i] = -s;
        }
        float a = K[0], b = K[1], c = K[2], d = K[3], e = K[4], f = K[5],
              g = K[6], h = K[7], ii = K[8];
        float det = a * (e * ii - f * h) - b * (d * ii - f * g) + c * (d * h - e * g);
        float id = 1.0f / det;
        o[12 + 0] = (e * ii - f * h) * id; o[12 + 1] = (c * h - b * ii) * id; o[12 + 2] = (b * f - c * e) * id;
        o[12 + 3] = (f * g - d * ii) * id; o[12 + 4] = (a * ii - c * g) * id; o[12 + 5] = (c * d - a * f) * id;
        o[12 + 6] = (d * h - e * g) * id; o[12 + 7] = (b * g - a * h) * id; o[12 + 8] = (a * e - b * d) * id;
        float det2 = a * e - b * d;
        float i00 = e / det2, i01 = -b / det2, i10 = -d / det2, i11 = a / det2;
        float ps0 = 1.0f / (float)(*pw), ps1 = 1.0f / (float)(*ph);
        o[21] = 0.1f * ((i00 + i10) * ps0 + (i01 + i11) * ps1);
    }
}

template <int NB>
__device__ __forceinline__ void apply_D(const float* __restrict__ D,
                                        const float* __restrict__ si,
                                        float* __restrict__ so) {
#pragma unroll
    for (int m = 0; m < NB; m++) {
        float acc = 0.f;
#pragma unroll
        for (int k = 0; k < NB; k++) acc += D[m * NB + k] * si[k];
        so[m] = acc;
    }
}

// ZERO-BARRIER wave-autonomous kernel. Each wave owns 16 records and a
// private LDS union region: stage (global_load_lds, linear) -> per-wave
// vmcnt(0) -> per-lane role split (lane = rec + 16*role: role0 geometry,
// roles1-3 one SH channel) -> write back in output layout -> nt copy-out.
// Wave lockstep + in-order DS ops make cross-lane LDS use safe without
// barriers; vd is loaded wave-redundantly (same values, no race).
__global__ __launch_bounds__(NTHR, 6) void adapter_kernel(
    const float* __restrict__ pg, const float* __restrict__ pc,
    const float* __restrict__ ops, const float* __restrict__ deps,
    const float* __restrict__ vdg, float* __restrict__ out,
    int R, long long N)
{
    __shared__ __align__(16) float lds[4 * WV_F];
    __shared__ float vd[VSZ];

    int lane = threadIdx.x & 63;
    int wid  = threadIdx.x >> 6;
    int bv   = blockIdx.y;

    // wave-redundant vd load: each wave writes (same) values, reads only after
    // its own in-order DS writes -> no barrier needed
    for (int i = lane; i < 186; i += 64) vd[i] = vdg[bv * VSZ + i];

    int r0 = blockIdx.x * (4 * WRECS) + wid * WRECS;
    int cnt = R - r0; if (cnt > WRECS) cnt = WRECS;
    if (cnt <= 0) return;                       // no barriers in kernel: safe
    float* W = lds + wid * WV_F;
    long long gb = (long long)bv * R + r0;

    // ---- per-wave staging: 1312 floats = 328 float4, linear ----
    const float* src = pg + gb * 82;
    if (cnt == WRECS) {
        const float4* s4 = (const float4*)src;   // gb*328 % 16 == 0
        float4* d4 = (float4*)W;
#pragma unroll
        for (int k = 0; k < 5; k++) g2lds16(s4 + k * 64 + lane, d4 + k * 64 + lane);
        if (lane < 8) g2lds16(s4 + 320 + lane, d4 + 320 + lane);
    } else {
        for (int f = lane; f < cnt * 82; f += 64) W[f] = src[f];
    }
    asm volatile("s_waitcnt vmcnt(0)" ::: "memory");   // wave's staging done
    __builtin_amdgcn_sched_barrier(0);

    // ---- read phase (all reads precede all writes in program order) ----
    int rec  = lane & 15;
    int role = lane >> 4;
    bool active = rec < cnt;
    long long g = gb + rec;
    const float* row = W + rec * 82;

    float rin[25];
    float depth = 0.f, opac = 0.f, px = 0.f, py = 0.f;
    if (active) {
        if (role == 0) {
#pragma unroll
            for (int i = 0; i < 7; i++) rin[i] = row[i];
            depth = deps[g];
            opac  = ops[g];
            float2 pxy = ((const float2*)pc)[g];
            px = pxy.x; py = pxy.y;
        } else {
            int cb = 7 + 25 * (role - 1);
#pragma unroll
            for (int m = 0; m < 25; m++) rin[m] = row[cb + m];
        }
    }

    // ---- compute + write back into W in OUTPUT layout ----
    if (active) {
        if (role == 0) {
            float sadj = vd[21];
            float sc[3];
#pragma unroll
            for (int i = 0; i < 3; i++) {
                float sg = 1.0f / (1.0f + expf(-rin[i]));
                sc[i] = (0.01f + 99.99f * sg) * depth * sadj;
            }
            float qw = rin[3], qx = rin[4], qy = rin[5], qz = rin[6];
            float qn = rsqrtf(qw * qw + qx * qx + qy * qy + qz * qz);
            qw *= qn; qx *= qn; qy *= qn; qz *= qn;
            float Rq[3][3];
            Rq[0][0] = 1.f - 2.f * (qy * qy + qz * qz);
            Rq[0][1] = 2.f * (qx * qy - qw * qz);
            Rq[0][2] = 2.f * (qx * qz + qw * qy);
            Rq[1][0] = 2.f * (qx * qy + qw * qz);
            Rq[1][1] = 1.f - 2.f * (qx * qx + qz * qz);
            Rq[1][2] = 2.f * (qy * qz - qw * qx);
            Rq[2][0] = 2.f * (qx * qz - qw * qy);
            Rq[2][1] = 2.f * (qy * qz + qw * qx);
            Rq[2][2] = 1.f - 2.f * (qx * qx + qy * qy);

            float Rc[3][3];
#pragma unroll
            for (int i = 0; i < 3; i++)
#pragma unroll
                for (int j = 0; j < 3; j++) Rc[i][j] = vd[i * 3 + j];

            float A[3][3];
#pragma unroll
            for (int i = 0; i < 3; i++)
#pragma unroll
                for (int k = 0; k < 3; k++)
                    A[i][k] = Rc[i][0] * Rq[0][k] + Rc[i][1] * Rq[1][k] + Rc[i][2] * Rq[2][k];
            float s2[3] = {sc[0] * sc[0], sc[1] * sc[1], sc[2] * sc[2]};

            float dx = vd[12] * px + vd[13] * py + vd[14];
            float dy = vd[15] * px + vd[16] * py + vd[17];
            float dz = vd[18] * px + vd[19] * py + vd[20];
            float dn = rsqrtf(dx * dx + dy * dy + dz * dz);
            dx *= dn; dy *= dn; dz *= dn;
            float rdx = Rc[0][0] * dx + Rc[0][1] * dy + Rc[0][2] * dz;
            float rdy = Rc[1][0] * dx + Rc[1][1] * dy + Rc[1][2] * dz;
            float rdz = Rc[2][0] * dx + Rc[2][1] * dy + Rc[2][2] * dz;

            W[WM + 3 * rec + 0] = vd[9]  + rdx * depth;
            W[WM + 3 * rec + 1] = vd[10] + rdy * depth;
            W[WM + 3 * rec + 2] = vd[11] + rdz * depth;
            W[WS + 3 * rec + 0] = sc[0];
            W[WS + 3 * rec + 1] = sc[1];
            W[WS + 3 * rec + 2] = sc[2];
#pragma unroll
            for (int i = 0; i < 3; i++)
#pragma unroll
                for (int j = 0; j < 3; j++)
                    W[WC + 9 * rec + i * 3 + j] =
                        A[i][0] * s2[0] * A[j][0] + A[i][1] * s2[1] * A[j][1] + A[i][2] * s2[2] * A[j][2];
            ((float4*)(W + WQ))[rec] = make_float4(qw, qx, qy, qz);
            W[WO + rec] = opac;
        } else {
            float so[25];
            so[0] = rin[0];
            apply_D<3>(vd + 22,  rin + 1,  so + 1);
            apply_D<5>(vd + 31,  rin + 4,  so + 4);
            apply_D<7>(vd + 56,  rin + 9,  so + 9);
            apply_D<9>(vd + 105, rin + 16, so + 16);
            float* dstsh = W + WSH + 75 * rec + 25 * (role - 1);
#pragma unroll
            for (int m = 0; m < 25; m++) dstsh[m] = so[m];
        }
    }

    // ---- per-wave copy-out: linear 16B nt streams per section ----
    if (cnt == WRECS) {
        const vf4* w4 = (const vf4*)W;
        vf4* dm  = (vf4*)(out +           3 * gb);
        vf4* dsc = (vf4*)(out +  3 * N +  3 * gb);
        vf4* dc  = (vf4*)(out +  6 * N +  9 * gb);
        vf4* dq  = (vf4*)(out + 15 * N +  4 * gb);
        vf4* dop = (vf4*)(out + 19 * N +      gb);
        vf4* dsh = (vf4*)(out + 20 * N + 75 * gb);
        if (lane < 12) __builtin_nontemporal_store(w4[WM / 4 + lane], dm + lane);
        if (lane < 12) __builtin_nontemporal_store(w4[WS / 4 + lane], dsc + lane);
        if (lane < 36) __builtin_nontemporal_store(w4[WC / 4 + lane], dc + lane);
        if (lane < 16) __builtin_nontemporal_store(w4[WQ / 4 + lane], dq + lane);
        if (lane < 4)  __builtin_nontemporal_store(w4[WO / 4 + lane], dop + lane);
#pragma unroll
        for (int k = 0; k < 4; k++)
            __builtin_nontemporal_store(w4[WSH / 4 + k * 64 + lane], dsh + k * 64 + lane);
        if (lane < 44) __builtin_nontemporal_store(w4[WSH / 4 + 256 + lane], dsh + 256 + lane);
    } else {
        float* dm  = out +           3 * gb;
        float* dsc = out +  3 * N +  3 * gb;
        float* dc  = out +  6 * N +  9 * gb;
        float* dq  = out + 15 * N +  4 * gb;
        float* dop = out + 19 * N +      gb;
        float* dsh = out + 20 * N + 75 * gb;
        for (int e = lane; e < cnt * 3;  e += 64) __builtin_nontemporal_store(W[WM + e], dm + e);
        for (int e = lane; e < cnt * 3;  e += 64) __builtin_nontemporal_store(W[WS + e], dsc + e);
        for (int e = lane; e < cnt * 9;  e += 64) __builtin_nontemporal_store(W[WC + e], dc + e);
        for (int e = lane; e < cnt * 4;  e += 64) __builtin_nontemporal_store(W[WQ + e], dq + e);
        for (int e = lane; e < cnt;      e += 64) __builtin_nontemporal_store(W[WO + e], dop + e);
        for (int e = lane; e < cnt * 75; e += 64) __builtin_nontemporal_store(W[WSH + e], dsh + e);
    }
}

extern "C" void kernel_launch(void* const* d_in, const int* in_sizes, int n_in,
                              void* d_out, int out_size, void* d_ws, size_t ws_size,
                              hipStream_t stream) {
    const float* pg   = (const float*)d_in[0];
    const float* pc   = (const float*)d_in[1];
    const float* ext  = (const float*)d_in[2];
    const float* intr = (const float*)d_in[3];
    const float* ops  = (const float*)d_in[4];
    const float* dep  = (const float*)d_in[5];
    const int*   ph   = (const int*)d_in[6];
    const int*   pw   = (const int*)d_in[7];

    int BV = in_sizes[2] / 16;               // extrinsics B*V*4*4
    long long N = (long long)in_sizes[4];    // opacities B*V*R
    int R = (int)(N / BV);

    float* vd = (float*)d_ws;
    setup_kernel<<<BV, 64, 0, stream>>>(ext, intr, ph, pw, vd);

    dim3 grid((R + 63) / 64, BV);            // 4 waves x 16 records per block
    adapter_kernel<<<grid, NTHR, 0, stream>>>(pg, pc, ops, dep, vd, (float*)d_out, R, N);
}

// Round 13
// 76.629 us; speedup vs baseline: 1.0379x; 1.0379x over previous
//
#include <hip/hip_runtime.h>

#define VSZ  192   // floats of per-view data (186 used, padded)
#define TILE 48    // records per block (LDS 19KB -> 8 blocks/CU -> 32 waves/CU)
#define NTHR 256
#define IN_F  (TILE * 82)   // 3936 floats, staged linearly
// output section offsets (floats) within the union LDS buffer:
#define SEC_M  0            // means  3*48 = 144
#define SEC_S  144          // scales 3*48 = 144
#define SEC_C  288          // cov    9*48 = 432
#define SEC_Q  720          // quats  4*48 = 192
#define SEC_O  912          // op     1*48 = 48
#define SEC_SH 960          // sh    75*48 = 3600
#define OUT_F  4560         // total (>= IN_F)

typedef float vf4 __attribute__((ext_vector_type(4)));   // legal nt-store operand

// ---------------- SH basis (degree 4, 25 components), float ----------------
__device__ __forceinline__ void sh_basis25(float x, float y, float z, float* Y) {
    float x2 = x * x, y2 = y * y, z2 = z * z;
    Y[0]  = 0.2820947918f;
    Y[1]  = 0.4886025119f * y;
    Y[2]  = 0.4886025119f * z;
    Y[3]  = 0.4886025119f * x;
    Y[4]  = 1.0925484306f * x * y;
    Y[5]  = 1.0925484306f * y * z;
    Y[6]  = 0.3153915653f * (3.0f * z2 - 1.0f);
    Y[7]  = 1.0925484306f * x * z;
    Y[8]  = 0.5462742153f * (x2 - y2);
    Y[9]  = 0.5900435899f * y * (3.0f * x2 - y2);
    Y[10] = 2.8906114426f * x * y * z;
    Y[11] = 0.4570457995f * y * (5.0f * z2 - 1.0f);
    Y[12] = 0.3731763326f * z * (5.0f * z2 - 3.0f);
    Y[13] = 0.4570457995f * x * (5.0f * z2 - 1.0f);
    Y[14] = 1.4453057213f * z * (x2 - y2);
    Y[15] = 0.5900435899f * x * (x2 - 3.0f * y2);
    Y[16] = 2.5033429418f * x * y * (x2 - y2);
    Y[17] = 1.7701307698f * y * z * (3.0f * x2 - y2);
    Y[18] = 0.9461746958f * x * y * (7.0f * z2 - 1.0f);
    Y[19] = 0.6690465436f * y * z * (7.0f * z2 - 3.0f);
    Y[20] = 0.1057855469f * (35.0f * z2 * z2 - 30.0f * z2 + 3.0f);
    Y[21] = 0.6690465436f * x * z * (7.0f * z2 - 3.0f);
    Y[22] = 0.4730873479f * (x2 - y2) * (7.0f * z2 - 1.0f);
    Y[23] = 1.7701307698f * x * z * (x2 - 3.0f * y2);
    Y[24] = 0.6258357354f * (x2 * x2 - 6.0f * x2 * y2 + y2 * y2);
}

// Per-view data layout (floats):
// [0:9) R_c2w  [9:12) cam_o  [12:21) Kinv  [21] scale_adj
// [22:31) D1   [31:56) D2    [56:105) D3   [105:186) D4
__global__ __launch_bounds__(64) void setup_kernel(
        const float* __restrict__ ext,
        const float* __restrict__ intr,
        const int* __restrict__ ph,
        const int* __restrict__ pw,
        float* __restrict__ vdg) {
    __shared__ float Bs[24][9];
    __shared__ float Yrs[24][9];
    __shared__ float normInv[24];

    int bv = blockIdx.x;
    int tid = threadIdx.x;
    const float* E = ext + bv * 16;
    const float* K = intr + bv * 9;
    float* o = vdg + bv * VSZ;

    const float z0 = 0.5f, r0 = 0.8660254037844386f;  // sqrt(3)/2
    const float TWO_PI = 6.283185307179586f;

    if (tid < 24) {
        int l, base;
        if      (tid < 3)  { l = 1; base = 0;  }
        else if (tid < 8)  { l = 2; base = 3;  }
        else if (tid < 15) { l = 3; base = 8;  }
        else               { l = 4; base = 15; }
        int n  = 2 * l + 1;
        int si = tid - base;
        int lo = l * l;
        float phs = 0.4f + TWO_PI * (float)si / (float)n;
        float sx = r0 * cosf(phs), sy = r0 * sinf(phs), sz = z0;
        float Y[25];
        sh_basis25(sx, sy, sz, Y);
        for (int k = 0; k < n; k++) Bs[tid][k] = Y[lo + k];
        float dx = E[0] * sx + E[1] * sy + E[2]  * sz;
        float dy = E[4] * sx + E[5] * sy + E[6]  * sz;
        float dz = E[8] * sx + E[9] * sy + E[10] * sz;
        sh_basis25(dx, dy, dz, Y);
        for (int k = 0; k < n; k++) Yrs[tid][k] = Y[lo + k];
    }
    __syncthreads();

    if (tid < 24) {
        int l, base;
        if      (tid < 3)  { l = 1; base = 0;  }
        else if (tid < 8)  { l = 2; base = 3;  }
        else if (tid < 15) { l = 3; base = 8;  }
        else               { l = 4; base = 15; }
        int n = 2 * l + 1;
        int m = tid - base;
        float acc = 0.f;
        for (int s = 0; s < n; s++) { float v = Bs[base + s][m]; acc += v * v; }
        normInv[tid] = 1.0f / acc;
    }
    __syncthreads();

    const int dofs[5] = {0, 22, 31, 56, 105};
    for (int e = tid; e < 164; e += 64) {
        int l, ebase, sbase;
        if      (e < 9)  { l = 1; ebase = 0;  sbase = 0;  }
        else if (e < 34) { l = 2; ebase = 9;  sbase = 3;  }
        else if (e < 83) { l = 3; ebase = 34; sbase = 8;  }
        else             { l = 4; ebase = 83; sbase = 15; }
        int n = 2 * l + 1;
        int el = e - ebase;
        int m = el / n, k = el % n;
        float acc = 0.f;
        for (int s = 0; s < n; s++) acc += Yrs[sbase + s][k] * Bs[sbase + s][m];
        o[dofs[l] + m * n + k] = acc * normInv[sbase + m];
    }

    if (tid == 0) {
        float Rw2c[3][3], Rc2w[3][3], t[3];
        for (int i = 0; i < 3; i++) {
            for (int j = 0; j < 3; j++) Rw2c[i][j] = E[i * 4 + j];
            t[i] = E[i * 4 + 3];
        }
        for (int i = 0; i < 3; i++)
            for (int j = 0; j < 3; j++) Rc2w[i][j] = Rw2c[j][i];
        for (int i = 0; i < 3; i++)
            for (int j = 0; j < 3; j++) o[i * 3 + j] = Rc2w[i][j];
        for (int i = 0; i < 3; i++) {
            float s = 0.f;
            for (int j = 0; j < 3; j++) s += Rc2w[i][j] * t[j];
            o[9 + i] = -s;
        }
        float a = K[0], b = K[1], c = K[2], d = K[3], e = K[4], f = K[5],
              g = K[6], h = K[7], ii = K[8];
        float det = a * (e * ii - f * h) - b * (d * ii - f * g) + c * (d * h - e * g);
        float id = 1.0f / det;
        o[12 + 0] = (e * ii - f * h) * id; o[12 + 1] = (c * h - b * ii) * id; o[12 + 2] = (b * f - c * e) * id;
        o[12 + 3] = (f * g - d * ii) * id; o[12 + 4] = (a * ii - c * g) * id; o[12 + 5] = (c * d - a * f) * id;
        o[12 + 6] = (d * h - e * g) * id; o[12 + 7] = (b * g - a * h) * id; o[12 + 8] = (a * e - b * d) * id;
        float det2 = a * e - b * d;
        float i00 = e / det2, i01 = -b / det2, i10 = -d / det2, i11 = a / det2;
        float ps0 = 1.0f / (float)(*pw), ps1 = 1.0f / (float)(*ph);
        o[21] = 0.1f * ((i00 + i10) * ps0 + (i01 + i11) * ps1);
    }
}

template <int NB>
__device__ __forceinline__ void apply_D(const float* __restrict__ D,
                                        const float* __restrict__ si,
                                        float* __restrict__ so) {
#pragma unroll
    for (int m = 0; m < NB; m++) {
        float acc = 0.f;
#pragma unroll
        for (int k = 0; k < NB; k++) acc += D[m * NB + k] * si[k];
        so[m] = acc;
    }
}

// Block = 256 threads, 48 records. Wave role-split: wave0 = geometry,
// waves1-3 = one SH channel each (lanes 48-63 of each wave idle in compute).
// LDS union ~19KB -> 8 blocks/CU -> 32 waves/CU (100% wave cap).
// nt output stores (no L2/RFO on the write stream).
__global__ __launch_bounds__(NTHR, 8) void adapter_kernel(
    const float* __restrict__ pg, const float* __restrict__ pc,
    const float* __restrict__ ops, const float* __restrict__ deps,
    const float* __restrict__ vdg, float* __restrict__ out,
    int R, long long N)
{
    __shared__ __align__(16) float tile[OUT_F];   // union: input(3936) / sections(4560)
    __shared__ float vd[VSZ];

    int bv = blockIdx.y;
    long long tilebase = (long long)bv * R + (long long)blockIdx.x * TILE;
    int cnt = R - blockIdx.x * TILE;
    if (cnt > TILE) cnt = TILE;
    bool full = (cnt == TILE);

    // ---- stage per-view constants + input tile (linear, float4) ----
    for (int i = threadIdx.x; i < 186; i += NTHR) vd[i] = vdg[bv * VSZ + i];

    const float* src = pg + tilebase * 82;
    if (full) {
        const float4* s4 = (const float4*)src;    // tilebase*328 % 16 == 0 (48*82*4 mult of 16)
        float4* t4 = (float4*)tile;
        for (int e = threadIdx.x; e < IN_F / 4; e += NTHR) t4[e] = s4[e];
    } else {
        for (int ff = threadIdx.x; ff < cnt * 82; ff += NTHR) tile[ff] = src[ff];
    }
    __syncthreads();

    // ---- read phase: each wave pulls its slice into registers ----
    int rec = threadIdx.x & 63;
    int sub = threadIdx.x >> 6;          // wave-uniform role
    bool active = rec < cnt;             // cnt <= 48 < 64: lanes 48-63 idle
    long long g = tilebase + rec;
    const float* row = tile + rec * 82;

    float gin[7];                         // sub0: raw geometry inputs
    float depth = 0.f, opac = 0.f, px = 0.f, py = 0.f;
    float si[25];                         // sub1..3: SH channel input

    if (sub == 0) {
        if (active) {
#pragma unroll
            for (int i = 0; i < 7; i++) gin[i] = row[i];
            depth = deps[g];
            opac  = ops[g];
            float2 pxy = ((const float2*)pc)[g];
            px = pxy.x; py = pxy.y;
        }
    } else {
        if (active) {
            int cb = 7 + 25 * (sub - 1);
#pragma unroll
            for (int m = 0; m < 25; m++) si[m] = row[cb + m];
        }
    }
    __syncthreads();   // all reads done before sections overwrite the buffer

    // ---- compute + write into per-section LDS arrays ----
    if (sub == 0) {
        if (active) {
            float sadj = vd[21];
            float sc[3];
#pragma unroll
            for (int i = 0; i < 3; i++) {
                float sg = 1.0f / (1.0f + expf(-gin[i]));
                sc[i] = (0.01f + 99.99f * sg) * depth * sadj;
            }
            float qw = gin[3], qx = gin[4], qy = gin[5], qz = gin[6];
            float qn = rsqrtf(qw * qw + qx * qx + qy * qy + qz * qz);
            qw *= qn; qx *= qn; qy *= qn; qz *= qn;
            float Rq[3][3];
            Rq[0][0] = 1.f - 2.f * (qy * qy + qz * qz);
            Rq[0][1] = 2.f * (qx * qy - qw * qz);
            Rq[0][2] = 2.f * (qx * qz + qw * qy);
            Rq[1][0] = 2.f * (qx * qy + qw * qz);
            Rq[1][1] = 1.f - 2.f * (qx * qx + qz * qz);
            Rq[1][2] = 2.f * (qy * qz - qw * qx);
            Rq[2][0] = 2.f * (qx * qz - qw * qy);
            Rq[2][1] = 2.f * (qy * qz + qw * qx);
            Rq[2][2] = 1.f - 2.f * (qx * qx + qy * qy);

            float Rc[3][3];
#pragma unroll
            for (int i = 0; i < 3; i++)
#pragma unroll
                for (int j = 0; j < 3; j++) Rc[i][j] = vd[i * 3 + j];

            float A[3][3];
#pragma unroll
            for (int i = 0; i < 3; i++)
#pragma unroll
                for (int k = 0; k < 3; k++)
                    A[i][k] = Rc[i][0] * Rq[0][k] + Rc[i][1] * Rq[1][k] + Rc[i][2] * Rq[2][k];
            float s2[3] = {sc[0] * sc[0], sc[1] * sc[1], sc[2] * sc[2]};

            float dx = vd[12] * px + vd[13] * py + vd[14];
            float dy = vd[15] * px + vd[16] * py + vd[17];
            float dz = vd[18] * px + vd[19] * py + vd[20];
            float dn = rsqrtf(dx * dx + dy * dy + dz * dz);
            dx *= dn; dy *= dn; dz *= dn;
            float rdx = Rc[0][0] * dx + Rc[0][1] * dy + Rc[0][2] * dz;
            float rdy = Rc[1][0] * dx + Rc[1][1] * dy + Rc[1][2] * dz;
            float rdz = Rc[2][0] * dx + Rc[2][1] * dy + Rc[2][2] * dz;

            tile[SEC_M + 3 * rec + 0] = vd[9]  + rdx * depth;
            tile[SEC_M + 3 * rec + 1] = vd[10] + rdy * depth;
            tile[SEC_M + 3 * rec + 2] = vd[11] + rdz * depth;
            tile[SEC_S + 3 * rec + 0] = sc[0];
            tile[SEC_S + 3 * rec + 1] = sc[1];
            tile[SEC_S + 3 * rec + 2] = sc[2];
#pragma unroll
            for (int i = 0; i < 3; i++)
#pragma unroll
                for (int j = 0; j < 3; j++)
                    tile[SEC_C + 9 * rec + i * 3 + j] =
                        A[i][0] * s2[0] * A[j][0] + A[i][1] * s2[1] * A[j][1] + A[i][2] * s2[2] * A[j][2];
            ((float4*)(tile + SEC_Q))[rec] = make_float4(qw, qx, qy, qz);
            tile[SEC_O + rec] = opac;
        }
    } else {
        if (active) {
            float so[25];
            so[0] = si[0];
            apply_D<3>(vd + 22,  si + 1,  so + 1);
            apply_D<5>(vd + 31,  si + 4,  so + 4);
            apply_D<7>(vd + 56,  si + 9,  so + 9);
            apply_D<9>(vd + 105, si + 16, so + 16);
            float* dstsh = tile + SEC_SH + 75 * rec + 25 * (sub - 1);
#pragma unroll
            for (int m = 0; m < 25; m++) dstsh[m] = so[m];
        }
    }
    __syncthreads();

    // ---- copy-out: pure linear 16B streams per section, NON-TEMPORAL ----
    if (full) {
        const vf4* t4 = (const vf4*)tile;
        vf4* dm  = (vf4*)(out +           3 * tilebase);
        vf4* ds  = (vf4*)(out +  3 * N +  3 * tilebase);
        vf4* dc  = (vf4*)(out +  6 * N +  9 * tilebase);
        vf4* dq  = (vf4*)(out + 15 * N +  4 * tilebase);
        vf4* dop = (vf4*)(out + 19 * N +      tilebase);
        vf4* dsh = (vf4*)(out + 20 * N + 75 * tilebase);
        int tid = threadIdx.x;
        if (tid < 36)  __builtin_nontemporal_store(t4[SEC_M / 4 + tid], dm + tid);
        if (tid < 36)  __builtin_nontemporal_store(t4[SEC_S / 4 + tid], ds + tid);
        if (tid < 108) __builtin_nontemporal_store(t4[SEC_C / 4 + tid], dc + tid);
        if (tid < 48)  __builtin_nontemporal_store(t4[SEC_Q / 4 + tid], dq + tid);
        if (tid < 12)  __builtin_nontemporal_store(t4[SEC_O / 4 + tid], dop + tid);
        for (int e = tid; e < 900; e += NTHR) __builtin_nontemporal_store(t4[SEC_SH / 4 + e], dsh + e);
    } else {
        int tid = threadIdx.x;
        float* dm  = out +           3 * tilebase;
        float* ds  = out +  3 * N +  3 * tilebase;
        float* dc  = out +  6 * N +  9 * tilebase;
        float* dq  = out + 15 * N +  4 * tilebase;
        float* dop = out + 19 * N +      tilebase;
        float* dsh = out + 20 * N + 75 * tilebase;
        for (int e = tid; e < cnt * 3;  e += NTHR) __builtin_nontemporal_store(tile[SEC_M + e], dm + e);
        for (int e = tid; e < cnt * 3;  e += NTHR) __builtin_nontemporal_store(tile[SEC_S + e], ds + e);
        for (int e = tid; e < cnt * 9;  e += NTHR) __builtin_nontemporal_store(tile[SEC_C + e], dc + e);
        for (int e = tid; e < cnt * 4;  e += NTHR) __builtin_nontemporal_store(tile[SEC_Q + e], dq + e);
        for (int e = tid; e < cnt;      e += NTHR) __builtin_nontemporal_store(tile[SEC_O + e], dop + e);
        for (int e = tid; e < cnt * 75; e += NTHR) __builtin_nontemporal_store(tile[SEC_SH + e], dsh + e);
    }
}

extern "C" void kernel_launch(void* const* d_in, const int* in_sizes, int n_in,
                              void* d_out, int out_size, void* d_ws, size_t ws_size,
                              hipStream_t stream) {
    const float* pg   = (const float*)d_in[0];
    const float* pc   = (const float*)d_in[1];
    const float* ext  = (const float*)d_in[2];
    const float* intr = (const float*)d_in[3];
    const float* ops  = (const float*)d_in[4];
    const float* dep  = (const float*)d_in[5];
    const int*   ph   = (const int*)d_in[6];
    const int*   pw   = (const int*)d_in[7];

    int BV = in_sizes[2] / 16;               // extrinsics B*V*4*4
    long long N = (long long)in_sizes[4];    // opacities B*V*R
    int R = (int)(N / BV);

    float* vd = (float*)d_ws;
    setup_kernel<<<BV, 64, 0, stream>>>(ext, intr, ph, pw, vd);

    dim3 grid((R + TILE - 1) / TILE, BV);
    adapter_kernel<<<grid, NTHR, 0, stream>>>(pg, pc, ops, dep, vd, (float*)d_out, R, N);
}